// Round 9
// baseline (194.131 us; speedup 1.0000x reference)
//
#include <hip/hip_runtime.h>

typedef unsigned short u16;
typedef unsigned int u32;
typedef __attribute__((ext_vector_type(8))) short short8;
typedef __attribute__((ext_vector_type(4))) short short4v;
typedef __attribute__((ext_vector_type(4))) float f32x4;

#define NB 2
#define NSEQ 2048
#define DIM 768
#define NH 12
#define HDIM 64

#define LOG2E 1.44269504088896f
#define CFOLD 0.18033688f /* 0.125 * log2(e) */

#if defined(__has_builtin)
#if __has_builtin(__builtin_amdgcn_exp2f)
#define EXPB(x) __builtin_amdgcn_exp2f(x)
#else
#define EXPB(x) exp2f(x)
#endif
#if __has_builtin(__builtin_amdgcn_rcpf)
#define RCP(x) __builtin_amdgcn_rcpf(x)
#else
#define RCP(x) (1.0f / (x))
#endif
#else
#define EXPB(x) exp2f(x)
#define RCP(x) (1.0f / (x))
#endif

__device__ __forceinline__ u16 f2bf(float x) {
    union { float f; unsigned u; } v; v.f = x;
    unsigned r = v.u + 0x7fffu + ((v.u >> 16) & 1u);
    return (u16)(r >> 16);
}

// RTNE pack (prep only)
__device__ __forceinline__ u32 pack_bf16(float a, float b) {
    union { float f; u32 u; } A, B; A.f = a; B.f = b;
    u32 ra = A.u + 0x7fffu + ((A.u >> 16) & 1u);
    u32 rb = B.u + 0x7fffu + ((B.u >> 16) & 1u);
    return __builtin_amdgcn_perm(rb, ra, 0x07060302u);
}

// cheap round-to-nearest pack: lo16 = a, hi16 = b
__device__ __forceinline__ u32 pack_rtn(float a, float b) {
    union { float f; u32 u; } A, B; A.f = a; B.f = b;
    return __builtin_amdgcn_perm(B.u + 0x8000u, A.u + 0x8000u, 0x07060302u);
}

#if defined(__has_builtin) && __has_builtin(__builtin_amdgcn_cvt_pk_bf16_f32)
__device__ __forceinline__ u32 pkbf(float a, float b) {
    auto r = __builtin_amdgcn_cvt_pk_bf16_f32(a, b);
    union { __typeof__(r) v; u32 u; } c; c.v = r;
    return c.u;
}
#else
#define pkbf pack_rtn
#endif

__device__ __forceinline__ f32x4 mfma16(short8 a, short8 b, f32x4 c) {
    return __builtin_amdgcn_mfma_f32_16x16x32_bf16(a, b, c, 0, 0, 0);
}

// K=16 bf16 MFMA: A,B = 4 bf16 (2 VGPRs). B-frag k-extent (quad*4+j) == S^T C-row group.
__device__ __forceinline__ f32x4 mfma1k(short4v a, short4v b, f32x4 c) {
    return __builtin_amdgcn_mfma_f32_16x16x16bf16_1k(a, b, c, 0, 0, 0);
}

__device__ __forceinline__ void glds16(const u16* g, u16* l) {
    __builtin_amdgcn_global_load_lds((const __attribute__((address_space(1))) u32*)g,
                                     (__attribute__((address_space(3))) u32*)l, 16, 0, 0);
}

// ---------------- fused prep: x->bf16 cast + both weight transposes ----------------
__global__ __launch_bounds__(256) void prep(const float* __restrict__ x, u16* __restrict__ xb,
                                            const float* __restrict__ qkv_w, u16* __restrict__ wq,
                                            const float* __restrict__ proj_w, u16* __restrict__ wp) {
    const int t = threadIdx.x;
    int bid = blockIdx.x;
    if (bid < 3072) {
        int i = (bid * 256 + t) * 4;
        float4 v = *(const float4*)(x + i);
        *(uint2*)(xb + i) = make_uint2(pack_bf16(v.x, v.y), pack_bf16(v.z, v.w));
        return;
    }
    const float* in; u16* outp; int rows, cols, bx, by;
    if (bid < 3072 + 1728) {
        bid -= 3072; in = qkv_w; outp = wq; rows = 768; cols = 2304;
        bx = bid % 72; by = bid / 72;
    } else {
        bid -= 4800; in = proj_w; outp = wp; rows = 768; cols = 768;
        bx = bid % 24; by = bid / 24;
    }
    __shared__ float tile[32][33];
    int c0 = bx * 32, r0 = by * 32;
    int tx = t & 31, ty = t >> 5;
    #pragma unroll
    for (int i = 0; i < 32; i += 8)
        tile[ty + i][tx] = in[(size_t)(r0 + ty + i) * cols + c0 + tx];
    __syncthreads();
    #pragma unroll
    for (int i = 0; i < 32; i += 8)
        outp[(size_t)(c0 + ty + i) * rows + r0 + tx] = f2bf(tile[tx][ty + i]);
}

// V [bh][n][64] -> V^T [bh][64][n]
__global__ __launch_bounds__(256) void vtrans(const u16* __restrict__ vin,
                                              u16* __restrict__ vout) {
    __shared__ __align__(16) u16 tile[64][72];
    const int bh = blockIdx.y;
    const int n0 = blockIdx.x * 64;
    const int t = threadIdx.x;
    const size_t base = (size_t)bh * NSEQ * HDIM;
    int r = t >> 3, cb = (t & 7) * 8;
    *(uint4*)&tile[r][cb]      = *(const uint4*)&vin[base + (size_t)(n0 + r) * HDIM + cb];
    *(uint4*)&tile[r + 32][cb] = *(const uint4*)&vin[base + (size_t)(n0 + r + 32) * HDIM + cb];
    __syncthreads();
    #pragma unroll
    for (int half = 0; half < 2; half++) {
        int d = (t >> 3) + half * 32;
        int nb = (t & 7) * 8;
        short8 v;
        #pragma unroll
        for (int j = 0; j < 8; j++) v[j] = (short)tile[nb + j][d];
        *(short8*)&vout[base + (size_t)d * NSEQ + n0 + nb] = v;
    }
}

// ---------------- QKV GEMM (single-buffer, 2-barrier; Q pre-scaled by CFOLD) --------
__global__ __launch_bounds__(256) void gemm_qkv(const u16* __restrict__ A,
                                                const u16* __restrict__ BT,
                                                const float* __restrict__ bias,
                                                u16* __restrict__ qo,
                                                u16* __restrict__ ko,
                                                u16* __restrict__ vo) {
    __shared__ __align__(16) u16 As[128 * 32];
    __shared__ __align__(16) u16 Bs[128 * 32];
    const int bm = blockIdx.y * 128, bn = blockIdx.x * 128;
    const int t = threadIdx.x;
    const int lane = t & 63, wave = t >> 6;
    const int l15 = lane & 15, quad = lane >> 4;
    const int wm = (wave >> 1) * 64, wn = (wave & 1) * 64;

    const u16* ga = A + (size_t)(bm + (t >> 2)) * DIM + (t & 3) * 8;
    const u16* gb = BT + (size_t)(bn + (t >> 2)) * DIM + (t & 3) * 8;
    u16* la = As + wave * 512;
    u16* lb = Bs + wave * 512;

    f32x4 acc[4][4] = {};
    for (int k0 = 0; k0 < DIM; k0 += 32) {
        __syncthreads();
        glds16(ga, la);
        glds16(ga + (size_t)64 * DIM, la + 2048);
        glds16(gb, lb);
        glds16(gb + (size_t)64 * DIM, lb + 2048);
        ga += 32; gb += 32;
        __syncthreads();
        short8 af[4], bf[4];
        #pragma unroll
        for (int i = 0; i < 4; i++) af[i] = *(const short8*)&As[(wm + i * 16 + l15) * 32 + quad * 8];
        #pragma unroll
        for (int j = 0; j < 4; j++) bf[j] = *(const short8*)&Bs[(wn + j * 16 + l15) * 32 + quad * 8];
        #pragma unroll
        for (int i = 0; i < 4; i++)
            #pragma unroll
            for (int j = 0; j < 4; j++)
                acc[i][j] = mfma16(af[i], bf[j], acc[i][j]);
    }

    const float cscale = (bn < DIM) ? CFOLD : 1.0f;   // fold 0.125*log2e into Q
    #pragma unroll
    for (int i = 0; i < 4; i++) {
        int mr = bm + wm + i * 16 + quad * 4;
        int b = mr >> 11, nn = mr & 2047;
        #pragma unroll
        for (int j = 0; j < 4; j++) {
            int ncol = bn + wn + j * 16 + l15;
            int w = ncol / DIM, rem = ncol - w * DIM;
            int h = rem >> 6, hd = rem & 63;
            u16* dst = (w == 0) ? qo : (w == 1) ? ko : vo;
            float bb = bias[ncol];
            size_t idx = (((size_t)(b * NH + h)) * NSEQ + nn) * HDIM + hd;
            #pragma unroll
            for (int r = 0; r < 4; r++)
                dst[idx + (size_t)r * HDIM] = f2bf((acc[i][j][r] + bb) * cscale);
        }
    }
}

// ---------------- fused region-gated attention ----------------
// 512 thr / 8 waves; wave (g,kh): q-group g=wave>>1 (16 rows), key-half kh=wave&1 (32 keys)
// P stays in registers via K=16 PV MFMA; gates from global mask loads, pipelined.
__global__ __launch_bounds__(512) void attn_kernel(const u16* __restrict__ Q,
                                                   const u16* __restrict__ Kg,
                                                   const u16* __restrict__ Vt,
                                                   const float* __restrict__ masks,
                                                   const float* __restrict__ lambda_r,
                                                   const float* __restrict__ theta_r,
                                                   const float* __restrict__ mask_w,
                                                   u16* __restrict__ AO) {
    const int bh = blockIdx.y;
    const int b = bh / NH, h = bh % NH;
    const int qb = blockIdx.x * 64;
    const int t = threadIdx.x, wave = t >> 6, lane = t & 63;
    const int l15 = lane & 15, quad = lane >> 4;
    const int g = wave >> 1, kh = wave & 1;

    __shared__ __align__(16) u16 pool[16384];   // Ks[2][4096] | Vs[2][4096]; epilogue O-exch
    __shared__ float Ls[8][16];

    const float lam = lambda_r[bh], th = theta_r[bh], mw = mask_w[bh];
    const float Bfac = lam * th * LOG2E;

    const size_t base = (size_t)bh * (NSEQ * HDIM);
    const int qrow = qb + g * 16;

    const u16* Qr = Q + base + (size_t)(qrow + l15) * HDIM;   // Q pre-scaled by CFOLD
    short8 bq0 = *(const short8*)(Qr + quad * 8);
    short8 bq1 = *(const short8*)(Qr + 32 + quad * 8);
    const float Afac = -lam * LOG2E * masks[bh * NSEQ + qrow + l15];

    // staging: 512 threads cover one 64x64 bf16 tile per glds16 (16 B each)
    const int srow = t >> 3;
    const int gc = (t & 7) ^ (srow & 7);
    const u16* kgp = Kg + base + (size_t)srow * HDIM + gc * 8;
    const u16* vgp = Vt + base + (size_t)srow * NSEQ + gc * 8;
    const int wbase = wave * 512;

    // K A-frag (16x16x32): row = kh*32 + c*16 + l15; d-chunk swizzled by l15&7
    const int ph = (quad ^ (l15 & 7)) * 8;
    const int krow0 = (kh * 32 + l15) * 64;          // c=0
    const int krow1 = (kh * 32 + 16 + l15) * 64;     // c=1
    // V A-frag (16x16x16): row = dt*16+l15; key chunk kh*4 + c*2 + (quad>>1), swizzled
    const int vsw = l15 & 7;
    const int vrow = l15 * 64 + (quad & 1) * 4;
    const int vch0 = ((kh * 4 + (quad >> 1)) ^ vsw) * 8;       // c=0
    const int vch1 = ((kh * 4 + 2 + (quad >> 1)) ^ vsw) * 8;   // c=1

    const float* mrow = masks + bh * NSEQ;

    float lsum = 0.f;
    f32x4 O[4] = {};

    // prologue: stage tile 0, load tile-0 key masks
    glds16(kgp, pool + wbase);
    glds16(vgp, pool + 8192 + wbase);
    float4 mk0 = *(const float4*)&mrow[kh * 32 + quad * 4];
    float4 mk1 = *(const float4*)&mrow[kh * 32 + 16 + quad * 4];

    const int NT = NSEQ / 64;
    for (int kt = 0; kt < NT; kt++) {
        const int bufofs = (kt & 1) * 4096;
        __syncthreads();
        float4 nk0 = mk0, nk1 = mk1;
        if (kt + 1 < NT) {
            glds16(kgp + (kt + 1) * 64 * HDIM, pool + (bufofs ^ 4096) + wbase);
            glds16(vgp + (kt + 1) * 64, pool + 8192 + (bufofs ^ 4096) + wbase);
            nk0 = *(const float4*)&mrow[(kt + 1) * 64 + kh * 32 + quad * 4];
            nk1 = *(const float4*)&mrow[(kt + 1) * 64 + kh * 32 + 16 + quad * 4];
        }
        const u16* KsB = pool + bufofs;
        const u16* VsB = pool + 8192 + bufofs;

        // gates (pure sigmoid; CFOLD lives in Q)
        float gp0[4], gp1[4];
        gp0[0] = RCP(1.0f + EXPB(fmaf(mk0.x, Afac, Bfac)));
        gp0[1] = RCP(1.0f + EXPB(fmaf(mk0.y, Afac, Bfac)));
        gp0[2] = RCP(1.0f + EXPB(fmaf(mk0.z, Afac, Bfac)));
        gp0[3] = RCP(1.0f + EXPB(fmaf(mk0.w, Afac, Bfac)));
        gp1[0] = RCP(1.0f + EXPB(fmaf(mk1.x, Afac, Bfac)));
        gp1[1] = RCP(1.0f + EXPB(fmaf(mk1.y, Afac, Bfac)));
        gp1[2] = RCP(1.0f + EXPB(fmaf(mk1.z, Afac, Bfac)));
        gp1[3] = RCP(1.0f + EXPB(fmaf(mk1.w, Afac, Bfac)));

        // S^T chunks (rows=key, cols=q), P packed straight into PV B-frags
        short8 a00 = *(const short8*)&KsB[krow0 + ph];
        short8 a01 = *(const short8*)&KsB[krow0 + (ph ^ 32)];
        short8 a10 = *(const short8*)&KsB[krow1 + ph];
        short8 a11 = *(const short8*)&KsB[krow1 + (ph ^ 32)];
        f32x4 S0 = {0.f, 0.f, 0.f, 0.f}, S1 = {0.f, 0.f, 0.f, 0.f};
        S0 = mfma16(a00, bq0, S0);
        S1 = mfma16(a10, bq0, S1);
        S0 = mfma16(a01, bq1, S0);
        S1 = mfma16(a11, bq1, S1);

        float p0[4], p1[4];
        #pragma unroll
        for (int r = 0; r < 4; r++) p0[r] = EXPB(S0[r] * gp0[r]);
        #pragma unroll
        for (int r = 0; r < 4; r++) p1[r] = EXPB(S1[r] * gp1[r]);
        lsum += (p0[0] + p0[1]) + (p0[2] + p0[3]) + (p1[0] + p1[1]) + (p1[2] + p1[3]);
        union { uint2 u; short4v s; } c0, c1;
        c0.u = make_uint2(pkbf(p0[0], p0[1]), pkbf(p0[2], p0[3]));
        c1.u = make_uint2(pkbf(p1[0], p1[1]), pkbf(p1[2], p1[3]));

        // PV: O^T[d][q] += V^T[d][k16] * P[k16][q], both 16-key chunks
        #pragma unroll
        for (int dt = 0; dt < 4; dt++) {
            short4v av0 = *(const short4v*)&VsB[vrow + dt * 1024 + vch0];
            short4v av1 = *(const short4v*)&VsB[vrow + dt * 1024 + vch1];
            O[dt] = mfma1k(av0, c0.s, O[dt]);
            O[dt] = mfma1k(av1, c1.s, O[dt]);
        }

        mk0 = nk0; mk1 = nk1;
    }

    // ---- combine wave pairs (kh=0 with kh=1) ----
    __syncthreads();
    float* Op = (float*)pool;                 // 8 waves x 64 lanes x 16 f32 = 32 KB
    const int slot = (wave * 64 + lane) * 16;
    #pragma unroll
    for (int dt = 0; dt < 4; dt++) *(f32x4*)&Op[slot + dt * 4] = O[dt];
    float ls = lsum;
    ls += __shfl_xor(ls, 16);
    ls += __shfl_xor(ls, 32);
    if (quad == 0) Ls[wave][l15] = ls;
    __syncthreads();
    if (kh == 0) {
        const int pslot = ((wave ^ 1) * 64 + lane) * 16;
        float sc = mw / (ls + Ls[wave ^ 1][l15]);
        u16* aor = AO + ((size_t)(b * NSEQ) + qrow + l15) * DIM + h * HDIM + quad * 4;
        #pragma unroll
        for (int dt = 0; dt < 4; dt++) {
            f32x4 oc = *(const f32x4*)&Op[pslot + dt * 4];
            float o0 = (O[dt][0] + oc[0]) * sc, o1 = (O[dt][1] + oc[1]) * sc;
            float o2 = (O[dt][2] + oc[2]) * sc, o3 = (O[dt][3] + oc[3]) * sc;
            *(uint2*)(aor + dt * 16) = make_uint2(pack_rtn(o0, o1), pack_rtn(o2, o3));
        }
    }
}

// ---------------- output projection GEMM (single-buffer, 2-barrier) ----------------
__global__ __launch_bounds__(256) void gemm_proj(const u16* __restrict__ A,
                                                 const u16* __restrict__ BT,
                                                 const float* __restrict__ bias,
                                                 float* __restrict__ outp) {
    __shared__ __align__(16) u16 As[128 * 32];
    __shared__ __align__(16) u16 Bs[64 * 32];
    const int bm = blockIdx.y * 128, bn = blockIdx.x * 64;
    const int t = threadIdx.x;
    const int lane = t & 63, wave = t >> 6;
    const int l15 = lane & 15, quad = lane >> 4;
    const int wm = wave * 32;

    const u16* ga = A + (size_t)(bm + (t >> 2)) * DIM + (t & 3) * 8;
    const u16* gb = BT + (size_t)(bn + (t >> 2)) * DIM + (t & 3) * 8;
    u16* la = As + wave * 512;
    u16* lb = Bs + wave * 512;

    f32x4 acc[2][4] = {};
    for (int k0 = 0; k0 < DIM; k0 += 32) {
        __syncthreads();
        glds16(ga, la);
        glds16(ga + (size_t)64 * DIM, la + 2048);
        glds16(gb, lb);
        ga += 32; gb += 32;
        __syncthreads();
        short8 af[2], bf[4];
        #pragma unroll
        for (int i = 0; i < 2; i++) af[i] = *(const short8*)&As[(wm + i * 16 + l15) * 32 + quad * 8];
        #pragma unroll
        for (int j = 0; j < 4; j++) bf[j] = *(const short8*)&Bs[(j * 16 + l15) * 32 + quad * 8];
        #pragma unroll
        for (int i = 0; i < 2; i++)
            #pragma unroll
            for (int j = 0; j < 4; j++)
                acc[i][j] = mfma16(af[i], bf[j], acc[i][j]);
    }

    #pragma unroll
    for (int i = 0; i < 2; i++) {
        int mr = bm + wm + i * 16 + quad * 4;
        #pragma unroll
        for (int j = 0; j < 4; j++) {
            int ncol = bn + j * 16 + l15;
            float bb = bias[ncol];
            #pragma unroll
            for (int r = 0; r < 4; r++)
                outp[(size_t)(mr + r) * DIM + ncol] = acc[i][j][r] + bb;
        }
    }
}

// ---------------- launch ----------------
extern "C" void kernel_launch(void* const* d_in, const int* in_sizes, int n_in,
                              void* d_out, int out_size, void* d_ws, size_t ws_size,
                              hipStream_t stream) {
    const float* x            = (const float*)d_in[0];
    const float* masks        = (const float*)d_in[1];
    const float* lambda_r     = (const float*)d_in[2];
    const float* theta_r      = (const float*)d_in[3];
    const float* mask_weights = (const float*)d_in[4];
    const float* qkv_w        = (const float*)d_in[5];
    const float* qkv_b        = (const float*)d_in[6];
    const float* proj_w       = (const float*)d_in[7];
    const float* proj_b       = (const float*)d_in[8];
    float* outp = (float*)d_out;

    const size_t SZH = (size_t)NB * NH * NSEQ * HDIM;
    u16* xb    = (u16*)d_ws;
    u16* wqkvT = xb + (size_t)4096 * 768;
    u16* wprT  = wqkvT + (size_t)2304 * 768;
    u16* qg    = wprT + (size_t)768 * 768;
    u16* kg    = qg + SZH;
    u16* vtmp  = kg + SZH;
    u16* vt    = vtmp + SZH;
    u16* ao    = xb;  // xb dead after gemm_qkv

    prep<<<dim3(3072 + 1728 + 576), 256, 0, stream>>>(x, xb, qkv_w, wqkvT, proj_w, wprT);
    gemm_qkv<<<dim3(2304 / 128, 4096 / 128), 256, 0, stream>>>(xb, wqkvT, qkv_b, qg, kg, vtmp);
    vtrans<<<dim3(NSEQ / 64, NB * NH), 256, 0, stream>>>(vtmp, vt);
    attn_kernel<<<dim3(NSEQ / 64, NB * NH), 512, 0, stream>>>(qg, kg, vt, masks, lambda_r,
                                                              theta_r, mask_weights, ao);
    gemm_proj<<<dim3(768 / 64, 4096 / 128), 256, 0, stream>>>(ao, wprT, proj_b, outp);
}

// Round 10
// 186.833 us; speedup vs baseline: 1.0391x; 1.0391x over previous
//
#include <hip/hip_runtime.h>

typedef unsigned short u16;
typedef unsigned int u32;
typedef __attribute__((ext_vector_type(8))) short short8;
typedef __attribute__((ext_vector_type(4))) float f32x4;

#define NB 2
#define NSEQ 2048
#define DIM 768
#define NH 12
#define HDIM 64

#define LOG2E 1.44269504088896f
#define CFOLD 0.18033688f /* 0.125 * log2(e) */

#if defined(__has_builtin)
#if __has_builtin(__builtin_amdgcn_exp2f)
#define EXPB(x) __builtin_amdgcn_exp2f(x)
#else
#define EXPB(x) exp2f(x)
#endif
#if __has_builtin(__builtin_amdgcn_rcpf)
#define RCP(x) __builtin_amdgcn_rcpf(x)
#else
#define RCP(x) (1.0f / (x))
#endif
#else
#define EXPB(x) exp2f(x)
#define RCP(x) (1.0f / (x))
#endif

__device__ __forceinline__ u16 f2bf(float x) {
    union { float f; unsigned u; } v; v.f = x;
    unsigned r = v.u + 0x7fffu + ((v.u >> 16) & 1u);
    return (u16)(r >> 16);
}

// RTNE pack (prep only)
__device__ __forceinline__ u32 pack_bf16(float a, float b) {
    union { float f; u32 u; } A, B; A.f = a; B.f = b;
    u32 ra = A.u + 0x7fffu + ((A.u >> 16) & 1u);
    u32 rb = B.u + 0x7fffu + ((B.u >> 16) & 1u);
    return __builtin_amdgcn_perm(rb, ra, 0x07060302u);
}

// cheap round-to-nearest pack: lo16 = a, hi16 = b
__device__ __forceinline__ u32 pack_rtn(float a, float b) {
    union { float f; u32 u; } A, B; A.f = a; B.f = b;
    return __builtin_amdgcn_perm(B.u + 0x8000u, A.u + 0x8000u, 0x07060302u);
}

__device__ __forceinline__ f32x4 mfma16(short8 a, short8 b, f32x4 c) {
    return __builtin_amdgcn_mfma_f32_16x16x32_bf16(a, b, c, 0, 0, 0);
}

__device__ __forceinline__ void glds16(const u16* g, u16* l) {
    __builtin_amdgcn_global_load_lds((const __attribute__((address_space(1))) u32*)g,
                                     (__attribute__((address_space(3))) u32*)l, 16, 0, 0);
}

// ---------------- fused prep: x->bf16 cast + both weight transposes ----------------
__global__ __launch_bounds__(256) void prep(const float* __restrict__ x, u16* __restrict__ xb,
                                            const float* __restrict__ qkv_w, u16* __restrict__ wq,
                                            const float* __restrict__ proj_w, u16* __restrict__ wp) {
    const int t = threadIdx.x;
    int bid = blockIdx.x;
    if (bid < 3072) {
        int i = (bid * 256 + t) * 4;
        float4 v = *(const float4*)(x + i);
        *(uint2*)(xb + i) = make_uint2(pack_bf16(v.x, v.y), pack_bf16(v.z, v.w));
        return;
    }
    const float* in; u16* outp; int rows, cols, bx, by;
    if (bid < 3072 + 1728) {
        bid -= 3072; in = qkv_w; outp = wq; rows = 768; cols = 2304;
        bx = bid % 72; by = bid / 72;
    } else {
        bid -= 4800; in = proj_w; outp = wp; rows = 768; cols = 768;
        bx = bid % 24; by = bid / 24;
    }
    __shared__ float tile[32][33];
    int c0 = bx * 32, r0 = by * 32;
    int tx = t & 31, ty = t >> 5;
    #pragma unroll
    for (int i = 0; i < 32; i += 8)
        tile[ty + i][tx] = in[(size_t)(r0 + ty + i) * cols + c0 + tx];
    __syncthreads();
    #pragma unroll
    for (int i = 0; i < 32; i += 8)
        outp[(size_t)(c0 + ty + i) * rows + r0 + tx] = f2bf(tile[tx][ty + i]);
}

// V [bh][n][64] -> V^T [bh][64][n]
__global__ __launch_bounds__(256) void vtrans(const u16* __restrict__ vin,
                                              u16* __restrict__ vout) {
    __shared__ __align__(16) u16 tile[64][72];
    const int bh = blockIdx.y;
    const int n0 = blockIdx.x * 64;
    const int t = threadIdx.x;
    const size_t base = (size_t)bh * NSEQ * HDIM;
    int r = t >> 3, cb = (t & 7) * 8;
    *(uint4*)&tile[r][cb]      = *(const uint4*)&vin[base + (size_t)(n0 + r) * HDIM + cb];
    *(uint4*)&tile[r + 32][cb] = *(const uint4*)&vin[base + (size_t)(n0 + r + 32) * HDIM + cb];
    __syncthreads();
    #pragma unroll
    for (int half = 0; half < 2; half++) {
        int d = (t >> 3) + half * 32;
        int nb = (t & 7) * 8;
        short8 v;
        #pragma unroll
        for (int j = 0; j < 8; j++) v[j] = (short)tile[nb + j][d];
        *(short8*)&vout[base + (size_t)d * NSEQ + n0 + nb] = v;
    }
}

// ---------------- QKV GEMM: BK=64 (12 iters, half the barrier drains), swizzled ----
// LDS rows are 128 B; global chunk c of row r stored at position c^(r&7); frag reads
// recover chunk kc*4+quad at position ((kc*4+quad)^(l15&7)) -> b128 bank floor.
__global__ __launch_bounds__(256) void gemm_qkv(const u16* __restrict__ A,
                                                const u16* __restrict__ BT,
                                                const float* __restrict__ bias,
                                                u16* __restrict__ qo,
                                                u16* __restrict__ ko,
                                                u16* __restrict__ vo) {
    __shared__ __align__(16) u16 As[128 * 64];
    __shared__ __align__(16) u16 Bs[128 * 64];
    const int bm = blockIdx.y * 128, bn = blockIdx.x * 128;
    const int t = threadIdx.x;
    const int lane = t & 63, wave = t >> 6;
    const int l15 = lane & 15, quad = lane >> 4;
    const int wm = (wave >> 1) * 64, wn = (wave & 1) * 64;

    // staging: row = t>>3 (0..31 per round), source chunk = (t&7) ^ (row&7)
    const int srow = t >> 3;
    const int sch = (t & 7) ^ (srow & 7);
    const u16* ga = A + (size_t)(bm + srow) * DIM + sch * 8;
    const u16* gb = BT + (size_t)(bn + srow) * DIM + sch * 8;
    const int ldst = wave * 512;   // u16; each glds16 covers 8 rows/wave
    const int fsw = l15 & 7;

    f32x4 acc[4][4] = {};
    for (int k0 = 0; k0 < DIM; k0 += 64) {
        __syncthreads();
        #pragma unroll
        for (int rnd = 0; rnd < 4; rnd++) {
            glds16(ga + (size_t)(rnd * 32) * DIM, As + rnd * 2048 + ldst);
            glds16(gb + (size_t)(rnd * 32) * DIM, Bs + rnd * 2048 + ldst);
        }
        ga += 64; gb += 64;
        __syncthreads();
        #pragma unroll
        for (int kc = 0; kc < 2; kc++) {
            short8 af[4], bf[4];
            #pragma unroll
            for (int i = 0; i < 4; i++)
                af[i] = *(const short8*)&As[(wm + i * 16 + l15) * 64 +
                                            (((kc * 4 + quad) ^ fsw) * 8)];
            #pragma unroll
            for (int j = 0; j < 4; j++)
                bf[j] = *(const short8*)&Bs[(wn + j * 16 + l15) * 64 +
                                            (((kc * 4 + quad) ^ fsw) * 8)];
            #pragma unroll
            for (int i = 0; i < 4; i++)
                #pragma unroll
                for (int j = 0; j < 4; j++)
                    acc[i][j] = mfma16(af[i], bf[j], acc[i][j]);
        }
    }

    #pragma unroll
    for (int i = 0; i < 4; i++) {
        int mr = bm + wm + i * 16 + quad * 4;
        int b = mr >> 11, nn = mr & 2047;
        #pragma unroll
        for (int j = 0; j < 4; j++) {
            int ncol = bn + wn + j * 16 + l15;
            int w = ncol / DIM, rem = ncol - w * DIM;
            int h = rem >> 6, hd = rem & 63;
            u16* dst = (w == 0) ? qo : (w == 1) ? ko : vo;
            float bb = bias[ncol];
            size_t idx = (((size_t)(b * NH + h)) * NSEQ + nn) * HDIM + hd;
            #pragma unroll
            for (int r = 0; r < 4; r++)
                dst[idx + (size_t)r * HDIM] = f2bf(acc[i][j][r] + bb);
        }
    }
}

// ---------------- fused region-gated attention (R8 version — measured 65.1 us) -----
// 512 thr / 8 waves; 64 q rows per block; wave (g,kh): q-group g=wave>>1, key-half kh=wave&1
__global__ __launch_bounds__(512) void attn_kernel(const u16* __restrict__ Q,
                                                   const u16* __restrict__ Kg,
                                                   const u16* __restrict__ Vt,
                                                   const float* __restrict__ masks,
                                                   const float* __restrict__ lambda_r,
                                                   const float* __restrict__ theta_r,
                                                   const float* __restrict__ mask_w,
                                                   u16* __restrict__ AO) {
    const int bh = blockIdx.y;
    const int b = bh / NH, h = bh % NH;
    const int qb = blockIdx.x * 64;
    const int t = threadIdx.x, wave = t >> 6, lane = t & 63;
    const int l15 = lane & 15, quad = lane >> 4;
    const int g = wave >> 1, kh = wave & 1;

    __shared__ __align__(16) u16 pool[16384];   // Ks[2][4096] | Vs[2][4096] (also epilogue O)
    __shared__ __align__(16) u16 Ps[8][640];    // per-wave P [16 q][40]
    __shared__ __align__(16) float mks[2][64];
    __shared__ float Ls[8][16];

    const float lam = lambda_r[bh], th = theta_r[bh], mw = mask_w[bh];
    const float Bfac = lam * th * LOG2E;

    const size_t base = (size_t)bh * (NSEQ * HDIM);
    const int qrow = qb + g * 16;

    const u16* Qr = Q + base + (size_t)(qrow + l15) * HDIM;
    short8 bq0 = *(const short8*)(Qr + quad * 8);
    short8 bq1 = *(const short8*)(Qr + 32 + quad * 8);
    const float Afac = -lam * LOG2E * masks[bh * NSEQ + qrow + l15];

    // staging: 512 threads cover one 64x64 bf16 tile per glds16 (16 B each)
    const int srow = t >> 3;
    const int gc = (t & 7) ^ (srow & 7);
    const u16* kgp = Kg + base + (size_t)srow * HDIM + gc * 8;
    const u16* vgp = Vt + base + (size_t)srow * NSEQ + gc * 8;
    const int wbase = wave * 512;

    const int ph = (quad ^ (l15 & 7)) * 8;
    const int vph = kh ? (ph ^ 32) : ph;     // V frag chunk for this wave's key half
    u16* PsW = Ps[wave];
    const int pw = l15 * 40 + quad * 4;      // + c*16
    const int prd = l15 * 40 + quad * 8;
    const float* mrow = masks + bh * NSEQ;

    float lsum = 0.f;
    f32x4 O[4] = {};

    glds16(kgp, pool + wbase);
    glds16(vgp, pool + 8192 + wbase);
    if (t < 16) *(float4*)&mks[0][t * 4] = *(const float4*)&mrow[t * 4];

    const int NT = NSEQ / 64;
    for (int kt = 0; kt < NT; kt++) {
        const int bufofs = (kt & 1) * 4096;
        __syncthreads();
        if (kt + 1 < NT) {
            glds16(kgp + (kt + 1) * 64 * HDIM, pool + (bufofs ^ 4096) + wbase);
            glds16(vgp + (kt + 1) * 64, pool + 8192 + (bufofs ^ 4096) + wbase);
            if (t < 16) *(float4*)&mks[(kt + 1) & 1][t * 4] =
                *(const float4*)&mrow[(kt + 1) * 64 + t * 4];
        }
        const u16* KsB = pool + bufofs;
        const u16* VsB = pool + 8192 + bufofs;
        const float* mkb = mks[kt & 1];

        // gates for this wave's 32 keys (off the S critical path)
        float gp[2][4];
        #pragma unroll
        for (int c = 0; c < 2; c++) {
            float4 mkv = *(const float4*)&mkb[kh * 32 + c * 16 + quad * 4];
            #pragma unroll
            for (int r = 0; r < 4; r++) {
                float mk = (r == 0) ? mkv.x : (r == 1) ? mkv.y : (r == 2) ? mkv.z : mkv.w;
                float e = EXPB(fmaf(mk, Afac, Bfac));
                gp[c][r] = CFOLD * RCP(1.0f + e);
            }
        }

        #pragma unroll
        for (int c = 0; c < 2; c++) {
            const int krow = kh * 32 + c * 16 + l15;
            short8 ak0 = *(const short8*)&KsB[krow * 64 + ph];
            short8 ak1 = *(const short8*)&KsB[krow * 64 + (ph ^ 32)];
            f32x4 S = {0.f, 0.f, 0.f, 0.f};
            S = mfma16(ak0, bq0, S);   // S^T: rows=key, cols=q
            S = mfma16(ak1, bq1, S);
            float p[4];
            #pragma unroll
            for (int r = 0; r < 4; r++) p[r] = EXPB(S[r] * gp[c][r]);
            lsum += (p[0] + p[1]) + (p[2] + p[3]);
            *(uint2*)&PsW[pw + c * 16] = make_uint2(pack_rtn(p[0], p[1]), pack_rtn(p[2], p[3]));
        }

        // PV over this wave's 32 keys: O^T[d][q] += V^T[d][k] * P[k][q]
        short8 bp = *(const short8*)&PsW[prd];
        #pragma unroll
        for (int dt = 0; dt < 4; dt++) {
            short8 av = *(const short8*)&VsB[(dt * 16 + l15) * 64 + vph];
            O[dt] = mfma16(av, bp, O[dt]);
        }
    }

    // ---- combine wave pairs (kh=0 with kh=1) ----
    __syncthreads();
    float* Op = (float*)pool;                 // 8 waves x 64 lanes x 16 f32 = 32 KB
    const int slot = (wave * 64 + lane) * 16;
    #pragma unroll
    for (int dt = 0; dt < 4; dt++) *(f32x4*)&Op[slot + dt * 4] = O[dt];
    float ls = lsum;
    ls += __shfl_xor(ls, 16);
    ls += __shfl_xor(ls, 32);
    if (quad == 0) Ls[wave][l15] = ls;
    __syncthreads();
    if (kh == 0) {
        const int pslot = ((wave ^ 1) * 64 + lane) * 16;
        float sc = mw / (ls + Ls[wave ^ 1][l15]);
        u16* aor = AO + ((size_t)(b * NSEQ) + qrow + l15) * DIM + h * HDIM + quad * 4;
        #pragma unroll
        for (int dt = 0; dt < 4; dt++) {
            f32x4 oc = *(const f32x4*)&Op[pslot + dt * 4];
            float o0 = (O[dt][0] + oc[0]) * sc, o1 = (O[dt][1] + oc[1]) * sc;
            float o2 = (O[dt][2] + oc[2]) * sc, o3 = (O[dt][3] + oc[3]) * sc;
            *(uint2*)(aor + dt * 16) = make_uint2(pack_rtn(o0, o1), pack_rtn(o2, o3));
        }
    }
}

// ---------------- output projection GEMM (128x64 tile, BK=64, swizzled) ------------
__global__ __launch_bounds__(256) void gemm_proj(const u16* __restrict__ A,
                                                 const u16* __restrict__ BT,
                                                 const float* __restrict__ bias,
                                                 float* __restrict__ outp) {
    __shared__ __align__(16) u16 As[128 * 64];
    __shared__ __align__(16) u16 Bs[64 * 64];
    const int bm = blockIdx.y * 128, bn = blockIdx.x * 64;
    const int t = threadIdx.x;
    const int lane = t & 63, wave = t >> 6;
    const int l15 = lane & 15, quad = lane >> 4;
    const int wm = wave * 32;

    const int srow = t >> 3;
    const int sch = (t & 7) ^ (srow & 7);
    const u16* ga = A + (size_t)(bm + srow) * DIM + sch * 8;
    const u16* gb = BT + (size_t)(bn + srow) * DIM + sch * 8;
    const int ldst = wave * 512;
    const int fsw = l15 & 7;

    f32x4 acc[2][4] = {};
    for (int k0 = 0; k0 < DIM; k0 += 64) {
        __syncthreads();
        #pragma unroll
        for (int rnd = 0; rnd < 4; rnd++)
            glds16(ga + (size_t)(rnd * 32) * DIM, As + rnd * 2048 + ldst);
        glds16(gb, Bs + ldst);
        glds16(gb + (size_t)32 * DIM, Bs + 2048 + ldst);
        ga += 64; gb += 64;
        __syncthreads();
        #pragma unroll
        for (int kc = 0; kc < 2; kc++) {
            short8 af[2], bf[4];
            #pragma unroll
            for (int i = 0; i < 2; i++)
                af[i] = *(const short8*)&As[(wm + i * 16 + l15) * 64 +
                                            (((kc * 4 + quad) ^ fsw) * 8)];
            #pragma unroll
            for (int j = 0; j < 4; j++)
                bf[j] = *(const short8*)&Bs[(j * 16 + l15) * 64 +
                                            (((kc * 4 + quad) ^ fsw) * 8)];
            #pragma unroll
            for (int i = 0; i < 2; i++)
                #pragma unroll
                for (int j = 0; j < 4; j++)
                    acc[i][j] = mfma16(af[i], bf[j], acc[i][j]);
        }
    }

    #pragma unroll
    for (int i = 0; i < 2; i++) {
        int mr = bm + wm + i * 16 + quad * 4;
        #pragma unroll
        for (int j = 0; j < 4; j++) {
            int ncol = bn + j * 16 + l15;
            float bb = bias[ncol];
            #pragma unroll
            for (int r = 0; r < 4; r++)
                outp[(size_t)(mr + r) * DIM + ncol] = acc[i][j][r] + bb;
        }
    }
}

// ---------------- launch ----------------
extern "C" void kernel_launch(void* const* d_in, const int* in_sizes, int n_in,
                              void* d_out, int out_size, void* d_ws, size_t ws_size,
                              hipStream_t stream) {
    const float* x            = (const float*)d_in[0];
    const float* masks        = (const float*)d_in[1];
    const float* lambda_r     = (const float*)d_in[2];
    const float* theta_r      = (const float*)d_in[3];
    const float* mask_weights = (const float*)d_in[4];
    const float* qkv_w        = (const float*)d_in[5];
    const float* qkv_b        = (const float*)d_in[6];
    const float* proj_w       = (const float*)d_in[7];
    const float* proj_b       = (const float*)d_in[8];
    float* outp = (float*)d_out;

    const size_t SZH = (size_t)NB * NH * NSEQ * HDIM;
    u16* xb    = (u16*)d_ws;
    u16* wqkvT = xb + (size_t)4096 * 768;
    u16* wprT  = wqkvT + (size_t)2304 * 768;
    u16* qg    = wprT + (size_t)768 * 768;
    u16* kg    = qg + SZH;
    u16* vtmp  = kg + SZH;
    u16* vt    = vtmp + SZH;
    u16* ao    = xb;  // xb dead after gemm_qkv

    prep<<<dim3(3072 + 1728 + 576), 256, 0, stream>>>(x, xb, qkv_w, wqkvT, proj_w, wprT);
    gemm_qkv<<<dim3(2304 / 128, 4096 / 128), 256, 0, stream>>>(xb, wqkvT, qkv_b, qg, kg, vtmp);
    vtrans<<<dim3(NSEQ / 64, NB * NH), 256, 0, stream>>>(vtmp, vt);
    attn_kernel<<<dim3(NSEQ / 64, NB * NH), 512, 0, stream>>>(qg, kg, vt, masks, lambda_r,
                                                              theta_r, mask_weights, ao);
    gemm_proj<<<dim3(768 / 64, 4096 / 128), 256, 0, stream>>>(ao, wprT, proj_b, outp);
}